// Round 4
// baseline (90.588 us; speedup 1.0000x reference)
//
#include <hip/hip_runtime.h>
#include <math.h>
#include <stdint.h>

#define LOG2E 1.44269504088896340736f
#define TPS 8      // j-tiles per super-step (2 chi DMAs/wave/step)
#define JS  8      // j-range splits -> NT=32 tiles/split, steps=4
#define NBUF 3     // triple-buffered chi staging (28 KB LDS -> 5 blocks/CU cap)
#define CUT -16.0f // skip exp when ALL entries have log2(K) < -16
                   // (K < 1.5e-5; dropped mass ~5e-5; measured absmax 0.0039 -> 3.5x margin)

// ROUND-8 LESSON (do not re-add): per-wave __threadfence() finisher -> cross-XCD
// L2 writebacks -> B refetched from HBM, 3x slower.
// ROUND-1 (-6.2us, best 84.9): counted-vmcnt + NBUF=3 + s_j folded + slabs.
// ROUND-2 (FAILED +6.1): L2-direct per-wave B loads (no LDS) -> 4x VMEM stream.
// ROUND-3 (FAILED +2.6): TPS=4/JS=8 "more blocks". VGPR (~100) caps 4 waves/SIMD,
// so residency never rose; halving TPS just doubled barrier density. The kernel
// is NOT TLP-starved -- it is per-wave issue/stall bound at ~4-5 blocks/CU.
//
// THIS ROUND: halve per-wave overhead at constant occupancy. 64 rows/wave
// (4 A-fragments) so each staged B fragment feeds 4 MFMAs; tile visits halve
// (320k->160k), barriers/wave halve (4 steps). sb table hoisted to prologue
// (round-3's one good piece) -> steady state exactly 2 DMAs/wave/step,
// uniform vmcnt(2).

typedef _Float16 f16x8 __attribute__((ext_vector_type(8)));
typedef float f32x4 __attribute__((ext_vector_type(4)));

__device__ __forceinline__ float softplus_f(float t) {
    return (t > 20.0f) ? t : log1pf(expf(t));
}

// global -> LDS direct DMA, 16 B/lane. lds base must be wave-uniform; HW adds lane*16.
#define GLDS16(g, l)                                                     \
    __builtin_amdgcn_global_load_lds(                                    \
        (const __attribute__((address_space(1))) uint32_t*)(const void*)(g), \
        (__attribute__((address_space(3))) uint32_t*)(void*)(l), 16, 0, 0)

// ---------------- pass 1: fragment-linear f16 B workspace + folded coeffs ----------------
// Tile jt, fragment pos l = q*16+m holds c[j=jt*16+m][k=q*8..q*8+7] as f16 ->
// wave B-load = base + lane*16 B (dense, DMA-compatible).
// sbG[j] = { beta_j * 2^s_j, CUT - s_j } with s_j = -0.5*log2e*|c_j|^2.
// Pad cols: beta'=0 and cut=+3e38 (branch never taken, contribution exactly 0).
__global__ void prep_c_kernel(const float* __restrict__ c,
                              const float* __restrict__ beta,
                              _Float16* __restrict__ chiF,
                              float2* __restrict__ sbG,
                              int M, int Mp) {
    int tid = blockIdx.x * blockDim.x + threadIdx.x;
    int j = tid >> 2, q = tid & 3;
    if (j >= Mp) return;
    int jt = j >> 4, m = j & 15;
    size_t fo = (size_t)jt * 512 + (size_t)(q * 16 + m) * 8;   // halves

    float ssq = 0.0f;
    _Float16 hi[8];
    if (j < M) {
        const float4* cp = (const float4*)(c + (size_t)j * 32 + q * 8);
        float4 a = cp[0], b = cp[1];
        float vv[8] = {a.x, a.y, a.z, a.w, b.x, b.y, b.z, b.w};
#pragma unroll
        for (int t = 0; t < 8; ++t) {
            float f = vv[t];
            ssq = fmaf(f, f, ssq);
            hi[t] = (_Float16)f;
        }
    } else {
#pragma unroll
        for (int t = 0; t < 8; ++t) hi[t] = (_Float16)0.0f;
    }
    ssq += __shfl_xor(ssq, 1, 4);       // |c_j|^2 over the 4 q-threads
    ssq += __shfl_xor(ssq, 2, 4);

    *(f16x8*)(chiF + fo) = *(const f16x8*)hi;
    if (q == 0) {
        if (j < M) {
            float s = -0.5f * LOG2E * ssq;
            sbG[j] = make_float2(beta[j] * exp2f(s), CUT - s);
        } else {
            sbG[j] = make_float2(0.0f, 3.0e38f);
        }
    }
}

// ---------------- main: LDS-staged MFMA RBF matvec, 64 rows/wave ----------------
// Block = 4 waves; wave w owns FOUR i-tiles (rows g*64..g*64+63, g = bx*4+w) ->
// each staged B fragment feeds 4 MFMAs. blockIdx.y picks 1/JS of the j-tiles
// (NT = 32 tiles, 4 super-steps of TPS=8).
// C layout (m89): col = lane&15, row = (lane>>4)*4 + reg.
// Prologue: 1 sb DMA/wave (whole split, 4 KB) + chi stage(0), stage(1).
// Steady state: wait vmcnt(2) [stage(s) done, stage(s+1) in flight] -> barrier
// -> issue stage(s+2) -> compute 8 tiles x 4 MFMAs. Drain-0 only on last step.
// Pad waves (g*64 >= N) run everything with clamped loads: barriers stay full.
__global__ __launch_bounds__(256) void krr_mfma_lds_kernel(
    const float* __restrict__ x,
    const _Float16* __restrict__ chiF,
    const float2* __restrict__ sbG,
    float* __restrict__ part,     // JS x N partial sums
    int N, int steps)             // super-steps per j-split (4)
{
    __shared__ f16x8 chiS[NBUF][TPS][64];              // 24 KB
    __shared__ __align__(16) float2 sbS[512];          // 4 KB (whole split, NT<=32)

    const int wave = threadIdx.x >> 6;
    const int lane = threadIdx.x & 63;
    const int m    = lane & 15;
    const int quad = lane >> 4;

    const int g  = blockIdx.x * 4 + wave;    // 64-row group
    const int s0 = blockIdx.y * steps;       // first super-step of this split

    // ---- prologue DMAs: whole-split sb (1 KB chunk = wave), chi stage(0), (1) ----
    auto stage = [&](int s, int b) {
        const _Float16* base = chiF + (size_t)(s0 + s) * TPS * 512;
#pragma unroll
        for (int ch = wave; ch < TPS; ch += 4)
            GLDS16(base + (size_t)ch * 512 + (size_t)lane * 8, &chiS[b][ch][0]);
    };
    {
        const char* sbsrc = (const char*)sbG + (size_t)s0 * TPS * 16 * 8;
        GLDS16(sbsrc + (size_t)wave * 1024 + (size_t)lane * 16, &sbS[wave * 128]);
    }
    stage(0, 0);
    if (steps > 1) stage(1, 1);

    // ---- four A fragments (rows g*64 + f*16 + m), pre-scaled by log2e ----
    // ainit[f][r] = a_i for C row quad*4+r; passed directly as MFMA C-in.
    f16x8 ahi[4];
    f32x4 ainit[4];
#pragma unroll
    for (int f = 0; f < 4; ++f) {
        int row = g * 64 + f * 16 + m;
        int rc = (row < N) ? row : (N - 1);  // clamp load; stores are guarded
        const float4* xp = (const float4*)(x + (size_t)rc * 32 + quad * 8);
        float4 v0 = xp[0], v1 = xp[1];
        float p = v0.x * v0.x + v0.y * v0.y + v0.z * v0.z + v0.w * v0.w
                + v1.x * v1.x + v1.y * v1.y + v1.z * v1.z + v1.w * v1.w;
        p += __shfl_xor(p, 16, 64);
        p += __shfl_xor(p, 32, 64);          // |x_row|^2 over all quads
        float ai_m = -0.5f * LOG2E * p;
        float vv[8] = {v0.x, v0.y, v0.z, v0.w, v1.x, v1.y, v1.z, v1.w};
#pragma unroll
        for (int t = 0; t < 8; ++t)
            ahi[f][t] = (_Float16)(vv[t] * LOG2E);
#pragma unroll
        for (int r = 0; r < 4; ++r)
            ainit[f][r] = __shfl(ai_m, quad * 4 + r, 16);
    }

    float outa[4][4] = {{0.0f}};

    int cb = 0;                              // compute buffer = s % NBUF
    for (int s = 0; s < steps; ++s) {
        // Counted wait: per-wave 2 loads/stage; at loop top the outstanding set
        // is stage(s) [2] + stage(s+1) [2] (prologue sb is older, retires first
        // in order). vmcnt(2) -> stage(s)+sb proven complete, stage(s+1) still
        // in flight. Barrier publishes all waves' chunks.
        if (s + 1 < steps) asm volatile("s_waitcnt vmcnt(2)\n\ts_barrier" ::: "memory");
        else               asm volatile("s_waitcnt vmcnt(0)\n\ts_barrier" ::: "memory");
        if (s + 2 < steps) {
            int nb = cb + 2; if (nb >= NBUF) nb -= NBUF;
            stage(s + 2, nb);                // buffer all waves finished reading
        }

#pragma unroll
        for (int t = 0; t < TPS; ++t) {
            f16x8 bhi = chiS[cb][t][lane];            // ds_read_b128, lane-linear
            float2 s2 = sbS[(s * TPS + t) * 16 + m];  // {beta'_j, cut_j}, broadcast
            // 4 independent MFMAs off one staged fragment; C-in = resident a_i.
            f32x4 accs[4];
            accs[0] = __builtin_amdgcn_mfma_f32_16x16x32_f16(ahi[0], bhi, ainit[0], 0, 0, 0);
            accs[1] = __builtin_amdgcn_mfma_f32_16x16x32_f16(ahi[1], bhi, ainit[1], 0, 0, 0);
            accs[2] = __builtin_amdgcn_mfma_f32_16x16x32_f16(ahi[2], bhi, ainit[2], 0, 0, 0);
            accs[3] = __builtin_amdgcn_mfma_f32_16x16x32_f16(ahi[3], bhi, ainit[3], 0, 0, 0);
#pragma unroll
            for (int f = 0; f < 4; ++f) {
                float mx = fmaxf(fmaxf(fmaxf(accs[f][0], accs[f][1]), accs[f][2]), accs[f][3]);
                if (__any(mx > s2.y)) {               // wave-uniform: s_cbranch skip
#pragma unroll
                    for (int r = 0; r < 4; ++r)
                        outa[f][r] = fmaf(s2.x, __builtin_amdgcn_exp2f(accs[f][r]), outa[f][r]);
                }
            }
        }
        cb = (cb + 1 == NBUF) ? 0 : cb + 1;
    }

    // ---- reduce over 16 cols (lane bits 0..3), plain store to this split's slab ----
#pragma unroll
    for (int f = 0; f < 4; ++f) {
        const int rowbase = g * 64 + f * 16;
#pragma unroll
        for (int r = 0; r < 4; ++r) {
            float v = outa[f][r];
            v += __shfl_xor(v, 1, 64);
            v += __shfl_xor(v, 2, 64);
            v += __shfl_xor(v, 4, 64);
            v += __shfl_xor(v, 8, 64);
            if (m == r) {
                int row = rowbase + quad * 4 + r;
                if (row < N) part[(size_t)blockIdx.y * N + row] = v;
            }
        }
    }
}

// ---------------- pass 3: sum JS partial slabs + softplus (deterministic) ----------------
__global__ void finish_kernel(const float* __restrict__ part,
                              float* __restrict__ out, int N) {
    int i4 = (blockIdx.x * blockDim.x + threadIdx.x) * 4;
    if (i4 + 3 < N) {
        float4 s = *(const float4*)(part + i4);
#pragma unroll
        for (int k = 1; k < JS; ++k) {
            float4 p = *(const float4*)(part + (size_t)k * N + i4);
            s.x += p.x; s.y += p.y; s.z += p.z; s.w += p.w;
        }
        *(float4*)(out + i4) = make_float4(softplus_f(s.x), softplus_f(s.y),
                                           softplus_f(s.z), softplus_f(s.w));
    } else if (i4 < N) {
        for (int u = i4; u < N && u < i4 + 4; ++u) {
            float s = 0.0f;
            for (int k = 0; k < JS; ++k) s += part[(size_t)k * N + u];
            out[u] = softplus_f(s);
        }
    }
}

// ---------------- fallback path (ws too small): round-1 VALU kernel ----------------
#define CHUNK_MAX 512
__global__ void zero_out_kernel(float* __restrict__ out, int n) {
    int i = blockIdx.x * blockDim.x + threadIdx.x;
    if (i < n) out[i] = 0.0f;
}
__global__ void softplus_kernel(float* __restrict__ out, int n) {
    int i = blockIdx.x * blockDim.x + threadIdx.x;
    if (i < n) out[i] = softplus_f(out[i]);
}
__global__ __launch_bounds__(64, 4) void krr_partial_kernel(
    const float* __restrict__ x, const float* __restrict__ c,
    const float* __restrict__ beta, float* __restrict__ out,
    int N, int M, int chunk)
{
    __shared__ float2 sw[CHUNK_MAX];
    const int lane = threadIdx.x;
    const int j0 = blockIdx.y * chunk;
    const int j1 = min(M, j0 + chunk);
    for (int j = j0 + lane; j < j1; j += 64) {
        const float4* cr = (const float4*)(c + (size_t)j * 32);
        float s = 0.0f;
#pragma unroll
        for (int q = 0; q < 8; ++q) {
            float4 v = cr[q];
            s = fmaf(v.x, v.x, s); s = fmaf(v.y, v.y, s);
            s = fmaf(v.z, v.z, s); s = fmaf(v.w, v.w, s);
        }
        sw[j - j0] = make_float2(-0.5f * LOG2E * s, beta[j]);
    }
    __syncthreads();
    const int i = blockIdx.x * 64 + lane;
    const bool valid = (i < N);
    const float4* xrow = (const float4*)(x + (size_t)(valid ? i : 0) * 32);
    float xr[32]; float xsq = 0.0f;
#pragma unroll
    for (int q = 0; q < 8; ++q) {
        float4 v = xrow[q];
        xsq = fmaf(v.x, v.x, xsq); xsq = fmaf(v.y, v.y, xsq);
        xsq = fmaf(v.z, v.z, xsq); xsq = fmaf(v.w, v.w, xsq);
        xr[4*q+0] = v.x * LOG2E; xr[4*q+1] = v.y * LOG2E;
        xr[4*q+2] = v.z * LOG2E; xr[4*q+3] = v.w * LOG2E;
    }
    const float ai = -0.5f * LOG2E * xsq;
    float acc = 0.0f;
#pragma unroll 2
    for (int j = j0; j < j1; ++j) {
        const float4* cr = (const float4*)(c + (size_t)j * 32);
        const float2 s2 = sw[j - j0];
        float d = ai + s2.x;
#pragma unroll
        for (int q = 0; q < 8; ++q) {
            float4 v = cr[q];
            d = fmaf(xr[4*q+0], v.x, d); d = fmaf(xr[4*q+1], v.y, d);
            d = fmaf(xr[4*q+2], v.z, d); d = fmaf(xr[4*q+3], v.w, d);
        }
        acc = fmaf(s2.y, __builtin_amdgcn_exp2f(d), acc);
    }
    if (valid) atomicAdd(out + i, acc);
}

extern "C" void kernel_launch(void* const* d_in, const int* in_sizes, int n_in,
                              void* d_out, int out_size, void* d_ws, size_t ws_size,
                              hipStream_t stream) {
    const float* x    = (const float*)d_in[0];   // (N, 32)
    const float* c    = (const float*)d_in[1];   // (M, 32)
    const float* beta = (const float*)d_in[2];   // (M,)
    float* out = (float*)d_out;                  // (N,)

    const int N = out_size;                      // 40000
    const int M = in_sizes[2];                   // 4000
    const int JT = (M + 15) / 16;                // 250 j-tiles
    const int SPAN = TPS * JS;                   // 64
    const int JTS = ((JT + SPAN - 1) / SPAN) * SPAN;  // padded: 256
    const int steps = JTS / SPAN;                // super-steps per j-split: 4
    const int Mp = JTS * 16;                     // 4096 padded cols

    // ws: chiF (JTS*512 halves) | sbG (Mp float2) | part (JS*N floats) ~ 1.57 MB
    const size_t chi_bytes = (size_t)JTS * 1024;
    const size_t sb_bytes  = (size_t)Mp * 8;
    const size_t need = chi_bytes + sb_bytes + (size_t)JS * N * 4;

    if (ws_size >= need) {
        _Float16* chiF = (_Float16*)d_ws;
        float2*   sbG  = (float2*)((char*)d_ws + chi_bytes);
        float*    part = (float*)((char*)d_ws + chi_bytes + sb_bytes);

        prep_c_kernel<<<dim3((Mp * 4 + 255) / 256), dim3(256), 0, stream>>>(
            c, beta, chiF, sbG, M, Mp);

        const int groups = (N + 63) / 64;            // 625 64-row groups
        const int bx = (groups + 3) / 4;             // 157 blocks x 4 waves
        krr_mfma_lds_kernel<<<dim3(bx, JS), dim3(256), 0, stream>>>(
            x, chiF, sbG, part, N, steps);

        const int fthreads = (N + 3) / 4;
        finish_kernel<<<dim3((fthreads + 255) / 256), dim3(256), 0, stream>>>(
            part, out, N);
    } else {
        zero_out_kernel<<<dim3((N + 255) / 256), dim3(256), 0, stream>>>(out, N);
        int jc = (M + CHUNK_MAX - 1) / CHUNK_MAX;
        if (jc < 8) jc = 8;
        int chunk = (M + jc - 1) / jc;
        dim3 grid((N + 63) / 64, jc);
        krr_partial_kernel<<<grid, dim3(64), 0, stream>>>(x, c, beta, out, N, M, chunk);
        softplus_kernel<<<dim3((N + 255) / 256), dim3(256), 0, stream>>>(out, N);
    }
}